// Round 3
// baseline (130.448 us; speedup 1.0000x reference)
//
#include <hip/hip_runtime.h>

#define NLOG2E -1.44269504088896340736f

// Per-row tiny MLP, fully unrolled. Weights are read through raw uniform
// pointers so they lower to s_load -> SGPRs (no VGPR cost); only the 12
// c*(-log2e) prefolds live in VGPRs. 8 rows/thread for ILP across the
// serial mul->exp->add->rcp->mul activation chains.

__device__ __forceinline__ float swish_row(
    float x0, float x1,
    const float* __restrict__ W1, const float* __restrict__ b1,
    const float* __restrict__ a1, const float* ncl1,
    const float* __restrict__ W2, const float* __restrict__ b2,
    const float* __restrict__ a2, const float* ncl2,
    const float* __restrict__ W3, float bb3)
{
    float h[8];
#pragma unroll
    for (int j = 0; j < 8; ++j) {
        float t = fmaf(x0, W1[j], fmaf(x1, W1[8 + j], b1[j]));
        float s = __builtin_amdgcn_rcpf(
                      1.0f + __builtin_amdgcn_exp2f(ncl1[j] * t));
        h[j] = a1[j] * (t * s);
    }
    float o = bb3;
#pragma unroll
    for (int k = 0; k < 4; ++k) {
        float t = b2[k];
#pragma unroll
        for (int j = 0; j < 8; ++j) t = fmaf(h[j], W2[j * 4 + k], t);
        float s = __builtin_amdgcn_rcpf(
                      1.0f + __builtin_amdgcn_exp2f(ncl2[k] * t));
        o = fmaf(a2[k] * (t * s), W3[k], o);   // a2[k]*W3[k] hoisted by compiler
    }
    return o;
}

__global__ __launch_bounds__(256, 4) void PlaygroundModel_66365834658304_kernel(
    const float* __restrict__ x,
    const float* __restrict__ W1, const float* __restrict__ b1,
    const float* __restrict__ a1, const float* __restrict__ c1,
    const float* __restrict__ W2, const float* __restrict__ b2,
    const float* __restrict__ a2, const float* __restrict__ c2,
    const float* __restrict__ W3, const float* __restrict__ b3,
    float* __restrict__ out, int rows)
{
    int tid = blockIdx.x * blockDim.x + threadIdx.x;
    long long base = (long long)tid * 8;
    if (base >= rows) return;

    float ncl1[8], ncl2[4];
#pragma unroll
    for (int j = 0; j < 8; ++j) ncl1[j] = c1[j] * NLOG2E;
#pragma unroll
    for (int k = 0; k < 4; ++k) ncl2[k] = c2[k] * NLOG2E;
    float bb3 = b3[0];

    if (base + 7 < rows) {
        const float4* x4 = (const float4*)x;
        float4 p0 = x4[(size_t)tid * 4 + 0];
        float4 p1 = x4[(size_t)tid * 4 + 1];
        float4 p2 = x4[(size_t)tid * 4 + 2];
        float4 p3 = x4[(size_t)tid * 4 + 3];
        float X0[8] = {p0.x, p0.z, p1.x, p1.z, p2.x, p2.z, p3.x, p3.z};
        float X1[8] = {p0.y, p0.w, p1.y, p1.w, p2.y, p2.w, p3.y, p3.w};
        float r[8];
#pragma unroll
        for (int rr = 0; rr < 8; ++rr)
            r[rr] = swish_row(X0[rr], X1[rr], W1, b1, a1, ncl1,
                              W2, b2, a2, ncl2, W3, bb3);
        float4* o4 = (float4*)out;
        o4[(size_t)tid * 2 + 0] = make_float4(r[0], r[1], r[2], r[3]);
        o4[(size_t)tid * 2 + 1] = make_float4(r[4], r[5], r[6], r[7]);
    } else {
        for (long long rr = base; rr < rows; ++rr) {
            float x0 = x[rr * 2 + 0], x1 = x[rr * 2 + 1];
            out[rr] = swish_row(x0, x1, W1, b1, a1, ncl1,
                                W2, b2, a2, ncl2, W3, bb3);
        }
    }
}

extern "C" void kernel_launch(void* const* d_in, const int* in_sizes, int n_in,
                              void* d_out, int out_size, void* d_ws, size_t ws_size,
                              hipStream_t stream) {
    const float* x  = (const float*)d_in[0];
    const float* W1 = (const float*)d_in[1];
    const float* b1 = (const float*)d_in[2];
    const float* a1 = (const float*)d_in[3];
    const float* c1 = (const float*)d_in[4];
    const float* W2 = (const float*)d_in[5];
    const float* b2 = (const float*)d_in[6];
    const float* a2 = (const float*)d_in[7];
    const float* c2 = (const float*)d_in[8];
    const float* W3 = (const float*)d_in[9];
    const float* b3 = (const float*)d_in[10];
    float* out = (float*)d_out;

    int rows  = in_sizes[0] / 2;
    int rows8 = (rows + 7) / 8;            // 8 rows per thread
    int block = 256;
    int grid  = (rows8 + block - 1) / block;

    PlaygroundModel_66365834658304_kernel<<<grid, block, 0, stream>>>(
        x, W1, b1, a1, c1, W2, b2, a2, c2, W3, b3, out, rows);
}